// Round 9
// baseline (277.877 us; speedup 1.0000x reference)
//
#include <hip/hip_runtime.h>
#include <hip/hip_bf16.h>

typedef __attribute__((ext_vector_type(8))) __bf16 bf16x8;
typedef __attribute__((ext_vector_type(4))) float f32x4;

#define NB 32768
#define HDIM 512
#define KDIM 1024

struct WPtrs { const float* wi[4]; const float* wh[4]; };
struct BPtrs { const float* bi[4]; const float* bh[4]; };

__device__ __forceinline__ float fsigmoid(float x) {
  return 1.0f / (1.0f + __expf(-x));
}
__device__ __forceinline__ float ftanh(float x) {
  return 2.0f / (1.0f + __expf(-2.0f * x)) - 1.0f;
}
__device__ __forceinline__ bf16x8 pack8(float4 a, float4 b) {
  bf16x8 r;
  r[0] = (__bf16)a.x; r[1] = (__bf16)a.y; r[2] = (__bf16)a.z; r[3] = (__bf16)a.w;
  r[4] = (__bf16)b.x; r[5] = (__bf16)b.y; r[6] = (__bf16)b.z; r[7] = (__bf16)b.w;
  return r;
}
__device__ __forceinline__ void gll16(const void* g, void* l) {
  __builtin_amdgcn_global_load_lds(
      (const __attribute__((address_space(1))) void*)g,
      (__attribute__((address_space(3))) void*)l, 16, 0, 0);
}
#define MFMA16(A, B, C) \
  C = __builtin_amdgcn_mfma_f32_16x16x32_bf16(A, B, C, 0, 0, 0)
#define SBAR() __builtin_amdgcn_s_barrier()
#define SCHED0() __builtin_amdgcn_sched_barrier(0)
#define LGKM(n) asm volatile("s_waitcnt lgkmcnt(" #n ")" ::: "memory")
#define VMCNT0() asm volatile("s_waitcnt vmcnt(0)" ::: "memory")

// ====================== prep (verified r1-r5) ======================
__global__ void pack_bias_kernel(BPtrs p, float* __restrict__ bias) {
  int idx = blockIdx.x * 256 + threadIdx.x;  // 0..2047
  int g = idx >> 9, np = idx & 511;
  bias[idx] = p.bi[g][np] + p.bh[g][np];
}

__global__ void conv_a_kernel(const float* __restrict__ x,
                              const float* __restrict__ h,
                              __bf16* __restrict__ Abf) {
  const size_t N8 = (size_t)NB * KDIM / 8;
  for (size_t i = (size_t)blockIdx.x * blockDim.x + threadIdx.x; i < N8;
       i += (size_t)gridDim.x * blockDim.x) {
    size_t e = i * 8;
    int k = (int)(e & (KDIM - 1));
    size_t r = e >> 10;
    const float* s = (k < 512) ? (x + r * 512 + k) : (h + r * 512 + (k - 512));
    float4 v0 = *(const float4*)s;
    float4 v1 = *(const float4*)(s + 4);
    *(bf16x8*)(Abf + e) = pack8(v0, v1);
  }
}

// Wt[p][k], p(np,g) = (np>>6)*256 + (g>>1)*128 + ((np>>4)&3)*32 + (g&1)*16 + (np&15)
__global__ void pack_w2_kernel(WPtrs p, __bf16* __restrict__ Wt) {
  __shared__ float tile[64][65];
  const int kt = blockIdx.x;
  const int nt = blockIdx.y;
  const int g = blockIdx.z;
  const int k0 = kt * 64, n0 = nt * 64;
  const float* src = (k0 < 512) ? p.wi[g] : p.wh[g];
  const int k0l = (k0 < 512) ? k0 : (k0 - 512);
  const int rr = threadIdx.x >> 6;
  const int cc = threadIdx.x & 63;
#pragma unroll
  for (int pp = 0; pp < 16; ++pp) {
    int kk = pp * 4 + rr;
    tile[kk][cc] = src[(size_t)(k0l + kk) * 512 + (n0 + cc)];
  }
  __syncthreads();
#pragma unroll
  for (int pp = 0; pp < 16; ++pp) {
    int nn = pp * 4 + rr;
    int np = n0 + nn;
    int prow = (np >> 6) * 256 + ((g >> 1) << 7) + (((np >> 4) & 3) << 5) +
               ((g & 1) << 4) + (np & 15);
    Wt[(size_t)prow * KDIM + (k0 + cc)] = (__bf16)tile[cc][nn];
  }
}

// Common per-kernel setup macro (identical geometry in real + diag kernels)
#define GEMM_SETUP()                                                          \
  __shared__ alignas(16) char lds[131072];                                    \
  const int tid = threadIdx.x;                                                \
  const int wid = tid >> 6;                                                   \
  const int wm = wid >> 2, wn = wid & 3;                                      \
  const int lane = tid & 63;                                                  \
  const int fc = lane & 15, fg = lane >> 4;                                   \
  const int bn = blockIdx.x & 7;                                              \
  const int bmg = blockIdx.x >> 3;                                            \
  const __bf16* Bsrc = Wt + (size_t)(bn * 256) * KDIM;                        \
  const int r0 = tid >> 3;                                                    \
  const int ssl = ((tid & 7) ^ (r0 & 7)) * 8;                                 \
  const uint32_t ldst0 = (uint32_t)(tid >> 6) * 1024;                         \
  auto stA = [&](int t, int h) {                                              \
    if (t < 64) {                                                             \
      const __bf16* g = Abf +                                                 \
                        ((size_t)((bmg << 2) + (t >> 4)) * 256 + h * 128 +    \
                         r0) * KDIM + (t & 15) * 64 + ssl;                    \
      uint32_t lb = (uint32_t)(t & 1) * 65536 + (uint32_t)h * 16384 + ldst0;  \
      gll16(g, (void*)&lds[lb]);                                              \
      gll16(g + (size_t)64 * KDIM, (void*)&lds[lb + 8192]);                   \
    }                                                                         \
  };                                                                          \
  auto stB = [&](int t, int h) {                                              \
    if (t < 64) {                                                             \
      const __bf16* g =                                                       \
          Bsrc + ((size_t)h * 128 + r0) * KDIM + (t & 15) * 64 + ssl;         \
      uint32_t lb =                                                           \
          (uint32_t)(t & 1) * 65536 + 32768 + (uint32_t)h * 16384 + ldst0;    \
      gll16(g, (void*)&lds[lb]);                                              \
      gll16(g + (size_t)64 * KDIM, (void*)&lds[lb + 8192]);                   \
    }                                                                         \
  };                                                                          \
  auto ldA = [&](int cb, int h, int mq, int ks) -> bf16x8 {                   \
    int row = wm * 64 + mq * 16 + fc;                                         \
    uint32_t off = (uint32_t)cb * 65536 + (uint32_t)h * 16384 +               \
                   (uint32_t)row * 128 +                                      \
                   (uint32_t)(((ks * 4 + fg) ^ (row & 7)) << 4);              \
    return *(const bf16x8*)&lds[off];                                         \
  };                                                                          \
  auto ldB = [&](int cb, int h, int nq, int ks) -> bf16x8 {                   \
    int row = wn * 32 + nq * 16 + fc;                                         \
    uint32_t off = (uint32_t)cb * 65536 + 32768 + (uint32_t)h * 16384 +       \
                   (uint32_t)row * 128 +                                      \
                   (uint32_t)(((ks * 4 + fg) ^ (row & 7)) << 4);              \
    return *(const bf16x8*)&lds[off];                                         \
  };                                                                          \
  f32x4 acc[8][4];                                                            \
  _Pragma("unroll") for (int m = 0; m < 8; ++m)                               \
      _Pragma("unroll") for (int n = 0; n < 4; ++n)                           \
          acc[m][n] = (f32x4){0.f, 0.f, 0.f, 0.f};                            \
  bf16x8 a[4][2], b0[2][2], b1[2][2];

#define Q_GROUP(AKS, BARR, ACCR, ACCC)                                        \
  __builtin_amdgcn_s_setprio(1);                                              \
  _Pragma("unroll") for (int mq = 0; mq < 4; ++mq)                            \
      _Pragma("unroll") for (int nq = 0; nq < 2; ++nq)                        \
          MFMA16(a[mq][AKS], BARR[nq][AKS], acc[ACCR + mq][ACCC + nq]);       \
  __builtin_amdgcn_s_setprio(0);

// ====================== real kernel: r5 + ks-outer MFMA order ======================
__global__ __launch_bounds__(512, 1) void lstm_gemm5b(
    const __bf16* __restrict__ Abf, const __bf16* __restrict__ Wt,
    const float* __restrict__ cin, const float* __restrict__ bias,
    float* __restrict__ out) {
  GEMM_SETUP();

  const int np = bn * 64 + wn * 16 + fc;
  const float bi = bias[np];
  const float bf_ = bias[512 + np];
  const float bg = bias[1024 + np];
  const float bo = bias[1536 + np];
  const size_t couts = (size_t)NB * HDIM;

  stA(0, 0); stA(0, 1); stB(0, 0); stB(0, 1);
  VMCNT0();
  SBAR();

#pragma unroll 2
  for (int t = 0; t < 64; ++t) {
    const int cb = t & 1;
    // 16 upfront reads, ks-major per operand (retire order matches staircase)
    b0[0][0] = ldB(cb, 0, 0, 0); b0[1][0] = ldB(cb, 0, 1, 0);  // 1-2
    b0[0][1] = ldB(cb, 0, 0, 1); b0[1][1] = ldB(cb, 0, 1, 1);  // 3-4
    a[0][0] = ldA(cb, 0, 0, 0); a[1][0] = ldA(cb, 0, 1, 0);    // 5-6
    a[2][0] = ldA(cb, 0, 2, 0); a[3][0] = ldA(cb, 0, 3, 0);    // 7-8
    a[0][1] = ldA(cb, 0, 0, 1); a[1][1] = ldA(cb, 0, 1, 1);    // 9-10
    a[2][1] = ldA(cb, 0, 2, 1); a[3][1] = ldA(cb, 0, 3, 1);    // 11-12
    b1[0][0] = ldB(cb, 1, 0, 0); b1[1][0] = ldB(cb, 1, 1, 0);  // 13-14
    b1[0][1] = ldB(cb, 1, 0, 1); b1[1][1] = ldB(cb, 1, 1, 1);  // 15-16
    stA(t + 1, 0); stA(t + 1, 1);
    LGKM(8); SCHED0();
    Q_GROUP(0, b0, 0, 0);  // Q1a: ks0, acc[0..3][0..1]
    LGKM(4); SCHED0();
    Q_GROUP(1, b0, 0, 0);  // Q1b: ks1 (dep distance 8)
    stB(t + 1, 0);
    LGKM(2); SCHED0();
    Q_GROUP(0, b1, 0, 2);  // Q2a
    LGKM(0); SCHED0();
    Q_GROUP(1, b1, 0, 2);  // Q2b
    stB(t + 1, 1);
    // reload a <- A half1, ks-major
    a[0][0] = ldA(cb, 1, 0, 0); a[1][0] = ldA(cb, 1, 1, 0);
    a[2][0] = ldA(cb, 1, 2, 0); a[3][0] = ldA(cb, 1, 3, 0);
    a[0][1] = ldA(cb, 1, 0, 1); a[1][1] = ldA(cb, 1, 1, 1);
    a[2][1] = ldA(cb, 1, 2, 1); a[3][1] = ldA(cb, 1, 3, 1);
    LGKM(4); SCHED0();
    Q_GROUP(0, b1, 4, 2);  // Q3a
    LGKM(0); SCHED0();
    Q_GROUP(1, b1, 4, 2);  // Q3b
    VMCNT0(); SCHED0();
    Q_GROUP(0, b0, 4, 0);  // Q4a (all-register)
    Q_GROUP(1, b0, 4, 0);  // Q4b
    SBAR();

    if ((t & 15) == 15) {
      const int g = t >> 4;
#pragma unroll
      for (int mf = 0; mf < 8; ++mf) {
        const int grow0 = ((bmg << 2) + g) * 256 + (mf >> 2) * 128 + wm * 64 +
                          (mf & 3) * 16 + fg * 4;
#pragma unroll
        for (int j = 0; j < 4; ++j) {
          const size_t off = (size_t)(grow0 + j) * HDIM + np;
          float i_ = fsigmoid(acc[mf][0][j] + bi);
          float f_ = fsigmoid(acc[mf][1][j] + bf_);
          float g_ = fsigmoid(acc[mf][2][j] + bg);
          float o_ = fsigmoid(acc[mf][3][j] + bo);
          float cp = f_ * cin[off] + i_ * g_;
          out[off] = o_ * ftanh(cp);
          out[couts + off] = cp;
        }
#pragma unroll
        for (int n = 0; n < 4; ++n) acc[mf][n] = (f32x4){0.f, 0.f, 0.f, 0.f};
      }
    }
  }
}

// ====================== diagnostics (write only to d_ws sink) ======================
// V3: pure MFMA pipe floor. 16 "tiles" x 64 MFMA/wave, no LDS ops in loop.
__global__ __launch_bounds__(512, 1) void diag_v3(
    const __bf16* __restrict__ Abf, const __bf16* __restrict__ Wt,
    float* __restrict__ sink) {
  GEMM_SETUP();
  stA(0, 0); stA(0, 1); stB(0, 0); stB(0, 1);
  VMCNT0();
  SBAR();
  // operands loaded once from real staged data (no const-folding possible)
#pragma unroll
  for (int mq = 0; mq < 4; ++mq)
#pragma unroll
    for (int ks = 0; ks < 2; ++ks) a[mq][ks] = ldA(0, 0, mq, ks);
#pragma unroll
  for (int nq = 0; nq < 2; ++nq)
#pragma unroll
    for (int ks = 0; ks < 2; ++ks) {
      b0[nq][ks] = ldB(0, 0, nq, ks);
      b1[nq][ks] = ldB(0, 1, nq, ks);
    }
  LGKM(0);
  SBAR();
#pragma unroll 2
  for (int t = 0; t < 16; ++t) {
    Q_GROUP(0, b0, 0, 0); Q_GROUP(1, b0, 0, 0);
    Q_GROUP(0, b1, 0, 2); Q_GROUP(1, b1, 0, 2);
    Q_GROUP(0, b1, 4, 2); Q_GROUP(1, b1, 4, 2);
    Q_GROUP(0, b0, 4, 0); Q_GROUP(1, b0, 4, 0);
  }
  float s = 0.f;
#pragma unroll
  for (int m = 0; m < 8; ++m)
#pragma unroll
    for (int n = 0; n < 4; ++n)
#pragma unroll
      for (int j = 0; j < 4; ++j) s += acc[m][n][j];
  sink[tid & 2047] = s;  // keep-alive (racy store OK: value unused)
}

// V2: ds_read staircase + barriers, NO staging/vmcnt in loop.
__global__ __launch_bounds__(512, 1) void diag_v2(
    const __bf16* __restrict__ Abf, const __bf16* __restrict__ Wt,
    float* __restrict__ sink) {
  GEMM_SETUP();
  stA(0, 0); stA(0, 1); stB(0, 0); stB(0, 1);  // init both buffers
  stA(1, 0); stA(1, 1); stB(1, 0); stB(1, 1);
  VMCNT0();
  SBAR();
#pragma unroll 2
  for (int t = 0; t < 16; ++t) {
    const int cb = t & 1;
    b0[0][0] = ldB(cb, 0, 0, 0); b0[1][0] = ldB(cb, 0, 1, 0);
    b0[0][1] = ldB(cb, 0, 0, 1); b0[1][1] = ldB(cb, 0, 1, 1);
    a[0][0] = ldA(cb, 0, 0, 0); a[1][0] = ldA(cb, 0, 1, 0);
    a[2][0] = ldA(cb, 0, 2, 0); a[3][0] = ldA(cb, 0, 3, 0);
    a[0][1] = ldA(cb, 0, 0, 1); a[1][1] = ldA(cb, 0, 1, 1);
    a[2][1] = ldA(cb, 0, 2, 1); a[3][1] = ldA(cb, 0, 3, 1);
    b1[0][0] = ldB(cb, 1, 0, 0); b1[1][0] = ldB(cb, 1, 1, 0);
    b1[0][1] = ldB(cb, 1, 0, 1); b1[1][1] = ldB(cb, 1, 1, 1);
    LGKM(8); SCHED0();
    Q_GROUP(0, b0, 0, 0);
    LGKM(4); SCHED0();
    Q_GROUP(1, b0, 0, 0);
    LGKM(2); SCHED0();
    Q_GROUP(0, b1, 0, 2);
    LGKM(0); SCHED0();
    Q_GROUP(1, b1, 0, 2);
    a[0][0] = ldA(cb, 1, 0, 0); a[1][0] = ldA(cb, 1, 1, 0);
    a[2][0] = ldA(cb, 1, 2, 0); a[3][0] = ldA(cb, 1, 3, 0);
    a[0][1] = ldA(cb, 1, 0, 1); a[1][1] = ldA(cb, 1, 1, 1);
    a[2][1] = ldA(cb, 1, 2, 1); a[3][1] = ldA(cb, 1, 3, 1);
    LGKM(4); SCHED0();
    Q_GROUP(0, b1, 4, 2);
    LGKM(0); SCHED0();
    Q_GROUP(1, b1, 4, 2);
    Q_GROUP(0, b0, 4, 0);
    Q_GROUP(1, b0, 4, 0);
    SBAR();
  }
  float s = 0.f;
#pragma unroll
  for (int m = 0; m < 8; ++m)
#pragma unroll
    for (int n = 0; n < 4; ++n)
#pragma unroll
      for (int j = 0; j < 4; ++j) s += acc[m][n][j];
  sink[tid & 2047] = s;
}

// V1: staging + vmcnt(0) + barriers, NO ds_reads in loop.
__global__ __launch_bounds__(512, 1) void diag_v1(
    const __bf16* __restrict__ Abf, const __bf16* __restrict__ Wt,
    float* __restrict__ sink) {
  GEMM_SETUP();
  stA(0, 0); stA(0, 1); stB(0, 0); stB(0, 1);
  VMCNT0();
  SBAR();
#pragma unroll
  for (int mq = 0; mq < 4; ++mq)
#pragma unroll
    for (int ks = 0; ks < 2; ++ks) a[mq][ks] = ldA(0, 0, mq, ks);
#pragma unroll
  for (int nq = 0; nq < 2; ++nq)
#pragma unroll
    for (int ks = 0; ks < 2; ++ks) {
      b0[nq][ks] = ldB(0, 0, nq, ks);
      b1[nq][ks] = ldB(0, 1, nq, ks);
    }
  LGKM(0);
  SBAR();
#pragma unroll 2
  for (int t = 0; t < 16; ++t) {
    stA(t + 1, 0); stA(t + 1, 1);
    Q_GROUP(0, b0, 0, 0); Q_GROUP(1, b0, 0, 0);
    stB(t + 1, 0);
    Q_GROUP(0, b1, 0, 2); Q_GROUP(1, b1, 0, 2);
    stB(t + 1, 1);
    Q_GROUP(0, b1, 4, 2); Q_GROUP(1, b1, 4, 2);
    VMCNT0(); SCHED0();
    Q_GROUP(0, b0, 4, 0); Q_GROUP(1, b0, 4, 0);
    SBAR();
  }
  float s = 0.f;
#pragma unroll
  for (int m = 0; m < 8; ++m)
#pragma unroll
    for (int n = 0; n < 4; ++n)
#pragma unroll
      for (int j = 0; j < 4; ++j) s += acc[m][n][j];
  sink[tid & 2047] = s;
}

// ====================== launch ======================
extern "C" void kernel_launch(void* const* d_in, const int* in_sizes, int n_in,
                              void* d_out, int out_size, void* d_ws,
                              size_t ws_size, hipStream_t stream) {
  const float* xin = (const float*)d_in[0];
  const float* hin = (const float*)d_in[1];
  const float* cin = (const float*)d_in[2];
  WPtrs wp;
  wp.wi[0] = (const float*)d_in[3];
  wp.wi[1] = (const float*)d_in[7];
  wp.wi[2] = (const float*)d_in[11];
  wp.wi[3] = (const float*)d_in[15];
  wp.wh[0] = (const float*)d_in[4];
  wp.wh[1] = (const float*)d_in[8];
  wp.wh[2] = (const float*)d_in[12];
  wp.wh[3] = (const float*)d_in[16];
  BPtrs bp;
  bp.bi[0] = (const float*)d_in[5];
  bp.bi[1] = (const float*)d_in[9];
  bp.bi[2] = (const float*)d_in[13];
  bp.bi[3] = (const float*)d_in[17];
  bp.bh[0] = (const float*)d_in[6];
  bp.bh[1] = (const float*)d_in[10];
  bp.bh[2] = (const float*)d_in[14];
  bp.bh[3] = (const float*)d_in[18];

  const size_t needA = (size_t)NB * KDIM * 2;    // 64 MiB
  const size_t needW = (size_t)2048 * KDIM * 2;  // 4 MiB

  __bf16* Abf = (__bf16*)d_ws;
  __bf16* Wt = (__bf16*)((char*)d_ws + needA);
  float* bias = (float*)((char*)d_ws + needA + needW);

  conv_a_kernel<<<2048, 256, 0, stream>>>(xin, hin, Abf);
  pack_w2_kernel<<<dim3(16, 8, 4), 256, 0, stream>>>(wp, Wt);
  pack_bias_kernel<<<8, 256, 0, stream>>>(bp, bias);
  lstm_gemm5b<<<256, 512, 0, stream>>>(Abf, Wt, cin, bias, (float*)d_out);
  // diagnostics AFTER the real kernel (bias already consumed; sink = bias area)
  diag_v3<<<256, 512, 0, stream>>>(Abf, Wt, bias);
  diag_v2<<<256, 512, 0, stream>>>(Abf, Wt, bias);
  diag_v1<<<256, 512, 0, stream>>>(Abf, Wt, bias);
}